// Round 8
// baseline (184.415 us; speedup 1.0000x reference)
//
#include <hip/hip_runtime.h>
#include <stdint.h>

#define NG   32
#define NPG  512
#define EPG  4096
#define DN   128
#define DP   64
#define NN   (NG*NPG)          // 16384 nodes
#define NE   (NG*EPG)          // 131072 edges
#define KD   320               // in_dim
#define HD   768               // hidden
#define SEQ  (1+NPG+EPG)       // 4609
#define TOK_ELEMS ((size_t)NG*SEQ*HD)
#define MASK_ELEMS ((size_t)NG*SEQ)

typedef unsigned short u16;
typedef __attribute__((ext_vector_type(8))) __bf16 bf16x8;
typedef __attribute__((ext_vector_type(8))) short  s16x8;
typedef __attribute__((ext_vector_type(4))) float  f32x4;

__device__ __forceinline__ u16 f2bf(float f) {
    uint32_t u = __builtin_bit_cast(uint32_t, f);
    u += 0x7fffu + ((u >> 16) & 1u);          // RNE
    return (u16)(u >> 16);
}

// B-tile LDS layout (per 8KB K-subtile of 128 W-rows x 32 k bf16): rows
// pair-packed into 128B lines, 16B k-slots XOR-swizzled by row-pair bits ->
// 16-row column-slice ds_read_b128 is 2-way (free, m136). Same formula on
// write and read side (both-sides-or-neither rule).
__device__ __forceinline__ int b_off(int row, int kb) {
    return ((row >> 1) << 7) + ((row & 1) << 6) + (kb ^ (((row >> 1) & 3) << 4));
}

// ---------------- aux kernels ----------------
// Exclusive prefix pointers via binary search (batch / edge graph ids are
// sorted non-decreasing per the reference's packing semantics).
__global__ void ptr_k(const int* __restrict__ batch, const int* __restrict__ eidx,
                      int* __restrict__ nptr, int* __restrict__ eptr) {
    int t = threadIdx.x;
    if (t < NG) {
        int g = t, lo = 0, hi = NN;
        while (lo < hi) { int mid = (lo + hi) >> 1; if (batch[mid] < g) lo = mid + 1; else hi = mid; }
        nptr[g] = lo;
    } else if (t < 2 * NG) {
        int g = t - NG, lo = 0, hi = NE;
        while (lo < hi) { int mid = (lo + hi) >> 1; if (batch[eidx[mid]] < g) lo = mid + 1; else hi = mid; }
        eptr[g] = lo;
    }
}

__global__ void wconv_k(const float* __restrict__ W, u16* __restrict__ Wb) {
    int i = blockIdx.x * 256 + threadIdx.x;
    if (i < KD * HD) Wb[i] = f2bf(W[i]);       // keep [H][K] row-major layout
}

__global__ void aux_k(const float* __restrict__ gt, float* __restrict__ out) {
    size_t i = (size_t)blockIdx.x * 256 + threadIdx.x;
    if (i < (size_t)NG * HD) {
        int g = (int)(i / HD), c = (int)(i % HD);
        out[(size_t)g * SEQ * HD + c] = gt[c];           // [graph] token row
    } else {
        size_t m = i - (size_t)NG * HD;
        if (m < MASK_ELEMS) out[TOK_ELEMS + m] = 1.0f;   // mask = True -> 1.0f
    }
}

// ---------------- main fused gather-GEMM-scatter ----------------
// block = 256 threads (4 waves), 128 A-rows per block; wave w owns rows
// [w*32, w*32+32) as two 16-row fragments; A in registers (2x10 bf16x8).
// B tiles: 16KB (128 W-rows x 64 k), double-buffered, reg-staged one phase
// ahead. MFMA computes D^T (operands swapped) so each lane's 4 acc regs are
// 4 consecutive N-cols of ONE token row -> f32x4 epilogue stores (16/lane/nt
// instead of 64 scalar): keeps the compiler's nt-boundary vmcnt wait
// encodable (<=63) so the store burst is never drained on the critical path.
__global__ __launch_bounds__(256, 2)
void gemm_scatter(const float* __restrict__ x,  const float* __restrict__ ea,
                  const float* __restrict__ P,  const float* __restrict__ EV,
                  const float* __restrict__ EEv,const float* __restrict__ bias,
                  const int* __restrict__ eidx, const int* __restrict__ batch,
                  const u16* __restrict__ Wb,   const int* __restrict__ nptr,
                  const int* __restrict__ eptr, float* __restrict__ out)
{
    __shared__ __align__(16) char b_lds[2][16384];   // 32 KB
    __shared__ int info_src[128], info_pu[128], info_pv[128], info_orow[128];

    const int tid  = threadIdx.x;
    const int lane = tid & 63;
    const int wid  = tid >> 6;
    const int lrow = lane & 15;
    const int lq   = lane >> 4;

    // ---- per-thread staging maps: 1024 16B-units = 128 rows x 8 k-chunks ----
    uint32_t g_off[4], l_off[4];
    #pragma unroll
    for (int i = 0; i < 4; ++i) {
        uint32_t u = (uint32_t)(i * 256 + tid);
        g_off[i] = (u >> 3) * (KD * 2) + (u & 7) * 16;
        l_off[i] = (((u >> 2) & 1) * 8192u) + (uint32_t)b_off(u >> 3, (u & 3) * 16);
    }
    const char* WbB = (const char*)Wb;

    const int r0  = blockIdx.x * 128;
    const bool isNode = (r0 < NN);     // NN % 128 == 0: uniform per block
    const float* feat = isNode ? x  : ea;
    const float* idv  = isNode ? EV : EEv;

    if (tid < 128) {
        int r = r0 + tid;
        if (isNode) {
            int g = batch[r];
            info_src[tid] = r; info_pu[tid] = r; info_pv[tid] = r;
            info_orow[tid] = g * SEQ + 1 + (r - nptr[g]);
        } else {
            int e = r - NN;
            int s = eidx[e], d = eidx[NE + e];
            int g = batch[s];
            info_src[tid] = e; info_pu[tid] = s; info_pv[tid] = d;
            info_orow[tid] = g * SEQ + 1 + NPG + (e - eptr[g]);
        }
    }
    __syncthreads();

    // ---- A fragments: gather + convert directly into registers ----
    bf16x8 afr[2][10];
    size_t obase[2];
    #pragma unroll
    for (int rb = 0; rb < 2; ++rb) {
        const int arow = wid * 32 + rb * 16 + lrow;
        const int fsrc = info_src[arow];
        const int pu   = info_pu[arow];
        const int pv   = info_pv[arow];
        #pragma unroll
        for (int s = 0; s < 10; ++s) {
            const int kg = s * 32 + lq * 8;   // 8-k slice, never straddles segments
            const float* sp;
            if      (s < 4) sp = feat + (size_t)fsrc * DN + kg;
            else if (s < 6) sp = P + (size_t)pu * DP + (kg - DN);
            else if (s < 8) sp = P + (size_t)pv * DP + (kg - DN - DP);
            else            sp = idv + (kg - DN - 2 * DP);
            f32x4 f0 = *reinterpret_cast<const f32x4*>(sp);
            f32x4 f1 = *reinterpret_cast<const f32x4*>(sp + 4);
            s16x8 v;
            v[0]=(short)f2bf(f0[0]); v[1]=(short)f2bf(f0[1]);
            v[2]=(short)f2bf(f0[2]); v[3]=(short)f2bf(f0[3]);
            v[4]=(short)f2bf(f1[0]); v[5]=(short)f2bf(f1[1]);
            v[6]=(short)f2bf(f1[2]); v[7]=(short)f2bf(f1[3]);
            afr[rb][s] = __builtin_bit_cast(bf16x8, v);
        }
        // token row for THIS lane's stores: indexed by lrow (D^T col = lane&15)
        obase[rb] = (size_t)info_orow[wid * 32 + rb * 16 + lrow] * HD;
    }

    const int roff = b_off(lrow, lq * 16);    // read-side swizzle, ni-invariant

    // prologue: stage tile 0 (nt=0, kp=0) into registers
    s16x8 pre[4];
    #pragma unroll
    for (int i = 0; i < 4; ++i)
        pre[i] = *reinterpret_cast<const s16x8*>(WbB + g_off[i]);

    int cur = 0;
    int nxt = 1;                       // next tile index (of 30)
    for (int nt = 0; nt < 6; ++nt) {
        const int n0 = nt * 128;
        f32x4 acc[2][8];
        #pragma unroll
        for (int rb = 0; rb < 2; ++rb)
            #pragma unroll
            for (int i = 0; i < 8; ++i) acc[rb][i] = (f32x4)0.f;

        #pragma unroll
        for (int kp = 0; kp < 5; ++kp) {
            cur ^= 1;
            char* bb = &b_lds[0][0] + cur * 16384;
            // write this phase's tile (staged one phase ago; vmem landed)
            #pragma unroll
            for (int i = 0; i < 4; ++i)
                *reinterpret_cast<s16x8*>(bb + l_off[i]) = pre[i];
            // issue next tile's loads (consumed next phase)
            {
                int tn  = (nxt < 30) ? nxt : 29; ++nxt;
                int ntn = tn / 5, kpn = tn - ntn * 5;
                const char* gb = WbB + (size_t)ntn * (128 * KD * 2) + kpn * 128;
                #pragma unroll
                for (int i = 0; i < 4; ++i)
                    pre[i] = *reinterpret_cast<const s16x8*>(gb + g_off[i]);
            }
            // make our ds_writes visible, then raw barrier (no vmcnt drain)
            asm volatile("s_waitcnt lgkmcnt(0)" ::: "memory");
            __builtin_amdgcn_sched_barrier(0);
            __builtin_amdgcn_s_barrier();
            #pragma unroll
            for (int kk = 0; kk < 2; ++kk) {
                const int kt = kp * 2 + kk;
                const char* bs = bb + kk * 8192;
                #pragma unroll
                for (int ni = 0; ni < 8; ++ni) {
                    bf16x8 bf = *reinterpret_cast<const bf16x8*>(bs + ni * 1024 + roff);
                    // operands SWAPPED: computes D^T -> lane regs hold 4
                    // consecutive N-cols of one token row.
                    acc[0][ni] = __builtin_amdgcn_mfma_f32_16x16x32_bf16(bf, afr[0][kt], acc[0][ni], 0, 0, 0);
                    acc[1][ni] = __builtin_amdgcn_mfma_f32_16x16x32_bf16(bf, afr[1][kt], acc[1][ni], 0, 0, 0);
                }
            }
            // reads of bb finish before our next lgkmcnt(0)+barrier, which
            // precedes any write to this buffer two phases later.
        }

        // ---- epilogue: bias + vectorized f32x4 scatter stores ----
        #pragma unroll
        for (int ni = 0; ni < 8; ++ni) {
            f32x4 bv = *reinterpret_cast<const f32x4*>(bias + n0 + ni * 16 + lq * 4);
            #pragma unroll
            for (int rb = 0; rb < 2; ++rb) {
                f32x4 v = acc[rb][ni] + bv;
                *reinterpret_cast<f32x4*>(out + obase[rb] + n0 + ni * 16 + lq * 4) = v;
            }
        }
    }
}

extern "C" void kernel_launch(void* const* d_in, const int* in_sizes, int n_in,
                              void* d_out, int out_size, void* d_ws, size_t ws_size,
                              hipStream_t stream) {
    const float* x    = (const float*)d_in[0];
    const float* ea   = (const float*)d_in[1];
    const float* P    = (const float*)d_in[2];
    const float* EV   = (const float*)d_in[3];
    const float* EEv  = (const float*)d_in[4];
    const float* W    = (const float*)d_in[5];
    const float* bias = (const float*)d_in[6];
    const float* gt   = (const float*)d_in[7];
    const int* eidx   = (const int*)d_in[8];
    const int* batch  = (const int*)d_in[9];

    float* out = (float*)d_out;
    u16* Wb  = (u16*)d_ws;
    int* ints = (int*)((char*)d_ws + (size_t)KD * HD * 2);
    int *nptr = ints, *eptr = ints + 32;

    ptr_k<<<1, 64, 0, stream>>>(batch, eidx, nptr, eptr);
    wconv_k<<<(KD * HD + 255) / 256, 256, 0, stream>>>(W, Wb);
    aux_k<<<(int)(((size_t)NG * HD + MASK_ELEMS + 255) / 256), 256, 0, stream>>>(gt, out);
    gemm_scatter<<<dim3((NN + NE) / 128), 256, 0, stream>>>(
        x, ea, P, EV, EEv, bias, eidx, batch, Wb, nptr, eptr, out);
}

// Round 9
// 169.013 us; speedup vs baseline: 1.0911x; 1.0911x over previous
//
#include <hip/hip_runtime.h>
#include <stdint.h>

#define NG   32
#define NPG  512
#define EPG  4096
#define DN   128
#define DP   64
#define NN   (NG*NPG)          // 16384 nodes
#define NE   (NG*EPG)          // 131072 edges
#define KD   320               // in_dim
#define HD   768               // hidden
#define SEQ  (1+NPG+EPG)       // 4609
#define TOK_ELEMS ((size_t)NG*SEQ*HD)
#define MASK_ELEMS ((size_t)NG*SEQ)

typedef unsigned short u16;
typedef __attribute__((ext_vector_type(8))) __bf16 bf16x8;
typedef __attribute__((ext_vector_type(8))) short  s16x8;
typedef __attribute__((ext_vector_type(4))) float  f32x4;

__device__ __forceinline__ u16 f2bf(float f) {
    uint32_t u = __builtin_bit_cast(uint32_t, f);
    u += 0x7fffu + ((u >> 16) & 1u);          // RNE
    return (u16)(u >> 16);
}

// B-tile LDS layout (per 4KB K-subtile of 64 W-rows x 32 k bf16): rows
// pair-packed into 128B lines, 16B k-slots XOR-swizzled by row-pair bits ->
// 16-row column-slice ds_read_b128 is 2-way (free, m136). Same formula on
// write and read side (both-sides-or-neither rule).
__device__ __forceinline__ int b_off(int row, int kb) {
    return ((row >> 1) << 7) + ((row & 1) << 6) + (kb ^ (((row >> 1) & 3) << 4));
}

// ---------------- aux kernels ----------------
__global__ void ptr_k(const int* __restrict__ batch, const int* __restrict__ eidx,
                      int* __restrict__ nptr, int* __restrict__ eptr) {
    int t = threadIdx.x;
    if (t < NG) {
        int g = t, lo = 0, hi = NN;
        while (lo < hi) { int mid = (lo + hi) >> 1; if (batch[mid] < g) lo = mid + 1; else hi = mid; }
        nptr[g] = lo;
    } else if (t < 2 * NG) {
        int g = t - NG, lo = 0, hi = NE;
        while (lo < hi) { int mid = (lo + hi) >> 1; if (batch[eidx[mid]] < g) lo = mid + 1; else hi = mid; }
        eptr[g] = lo;
    }
}

__global__ void wconv_k(const float* __restrict__ W, u16* __restrict__ Wb) {
    int i = blockIdx.x * 256 + threadIdx.x;
    if (i < KD * HD) Wb[i] = f2bf(W[i]);       // keep [H][K] row-major layout
}

__global__ void aux_k(const float* __restrict__ gt, float* __restrict__ out) {
    size_t i = (size_t)blockIdx.x * 256 + threadIdx.x;
    if (i < (size_t)NG * HD) {
        int g = (int)(i / HD), c = (int)(i % HD);
        out[(size_t)g * SEQ * HD + c] = gt[c];           // [graph] token row
    } else {
        size_t m = i - (size_t)NG * HD;
        if (m < MASK_ELEMS) out[TOK_ELEMS + m] = 1.0f;   // mask = True -> 1.0f
    }
}

// ---------------- main fused gather-GEMM-scatter ----------------
// block = 256 threads (4 waves), 128 A-rows per block; wave w owns rows
// [w*32, w*32+32) as two 16-row fragments; A in registers (2x10 bf16x8).
// N-tile 64 (12 nt), BK=64 phases, double-buffered 8KB B tiles, reg-staged
// one phase ahead. Previous nt's accumulator is stored by DRIBBLING 6-7
// scalar stores into every phase (after its MFMA cluster) so the CU's
// store stream is continuous instead of bursting at nt boundaries ->
// HBM-write time overlaps LDS/MFMA time.
__global__ __launch_bounds__(256, 2)
void gemm_scatter(const float* __restrict__ x,  const float* __restrict__ ea,
                  const float* __restrict__ P,  const float* __restrict__ EV,
                  const float* __restrict__ EEv,const float* __restrict__ bias,
                  const int* __restrict__ eidx, const int* __restrict__ batch,
                  const u16* __restrict__ Wb,   const int* __restrict__ nptr,
                  const int* __restrict__ eptr, float* __restrict__ out)
{
    __shared__ __align__(16) char b_lds[2][8192];    // 16 KB
    __shared__ int info_src[128], info_pu[128], info_pv[128], info_orow[128];

    const int tid  = threadIdx.x;
    const int lane = tid & 63;
    const int wid  = tid >> 6;
    const int lrow = lane & 15;
    const int lq   = lane >> 4;

    // ---- per-thread staging maps: 512 16B-units = 64 rows x 8 k-chunks ----
    uint32_t g_off[2], l_off[2];
    #pragma unroll
    for (int i = 0; i < 2; ++i) {
        uint32_t u = (uint32_t)(i * 256 + tid);      // u in [0,512)
        uint32_t row = u >> 3, c = u & 7;            // row<64, 16B chunk c<8
        g_off[i] = row * (KD * 2) + c * 16;
        l_off[i] = ((c >> 2) * 4096u) + (uint32_t)b_off((int)row, (int)((c & 3) * 16));
    }
    const char* WbB = (const char*)Wb;

    const int r0  = blockIdx.x * 128;
    const bool isNode = (r0 < NN);     // NN % 128 == 0: uniform per block
    const float* feat = isNode ? x  : ea;
    const float* idv  = isNode ? EV : EEv;

    if (tid < 128) {
        int r = r0 + tid;
        if (isNode) {
            int g = batch[r];
            info_src[tid] = r; info_pu[tid] = r; info_pv[tid] = r;
            info_orow[tid] = g * SEQ + 1 + (r - nptr[g]);
        } else {
            int e = r - NN;
            int s = eidx[e], d = eidx[NE + e];
            int g = batch[s];
            info_src[tid] = e; info_pu[tid] = s; info_pv[tid] = d;
            info_orow[tid] = g * SEQ + 1 + NPG + (e - eptr[g]);
        }
    }
    __syncthreads();

    // ---- A fragments: gather + convert directly into registers ----
    bf16x8 afr[2][10];
    int obase[2][4];
    #pragma unroll
    for (int rb = 0; rb < 2; ++rb) {
        const int arow = wid * 32 + rb * 16 + lrow;
        const int fsrc = info_src[arow];
        const int pu   = info_pu[arow];
        const int pv   = info_pv[arow];
        #pragma unroll
        for (int s = 0; s < 10; ++s) {
            const int kg = s * 32 + lq * 8;   // 8-k slice, never straddles segments
            const float* sp;
            if      (s < 4) sp = feat + (size_t)fsrc * DN + kg;
            else if (s < 6) sp = P + (size_t)pu * DP + (kg - DN);
            else if (s < 8) sp = P + (size_t)pv * DP + (kg - DN - DP);
            else            sp = idv + (kg - DN - 2 * DP);
            f32x4 f0 = *reinterpret_cast<const f32x4*>(sp);
            f32x4 f1 = *reinterpret_cast<const f32x4*>(sp + 4);
            s16x8 v;
            v[0]=(short)f2bf(f0[0]); v[1]=(short)f2bf(f0[1]);
            v[2]=(short)f2bf(f0[2]); v[3]=(short)f2bf(f0[3]);
            v[4]=(short)f2bf(f1[0]); v[5]=(short)f2bf(f1[1]);
            v[6]=(short)f2bf(f1[2]); v[7]=(short)f2bf(f1[3]);
            afr[rb][s] = __builtin_bit_cast(bf16x8, v);
        }
        #pragma unroll
        for (int j = 0; j < 4; ++j)
            obase[rb][j] = info_orow[wid * 32 + rb * 16 + lq * 4 + j] * HD;
    }

    const int roff = b_off(lrow, lq * 16);    // read-side swizzle, ni-invariant

    // prologue: stage tile 0 into registers
    s16x8 pre[2];
    #pragma unroll
    for (int i = 0; i < 2; ++i)
        pre[i] = *reinterpret_cast<const s16x8*>(WbB + g_off[i]);

    int cur = 0;
    int nxt = 1;                       // next tile index (of 60)

    // dribble schedule: 32 stores of the prev nt spread over 5 phases
    constexpr int S0[5] = {0, 7, 14, 20, 26};
    constexpr int S1[5] = {7, 14, 20, 26, 32};

    // one nt: compute into acc/bv, dribble-store accP/bvP (prev nt) if pn0>=0
    auto do_nt = [&](f32x4 (&acc)[2][4], float (&bv)[4],
                     f32x4 (&accP)[2][4], float (&bvP)[4],
                     int n0, int pn0) {
        #pragma unroll
        for (int rb = 0; rb < 2; ++rb)
            #pragma unroll
            for (int i = 0; i < 4; ++i) acc[rb][i] = (f32x4)0.f;
        #pragma unroll
        for (int ni = 0; ni < 4; ++ni)
            bv[ni] = bias[n0 + ni * 16 + lrow];   // used when this nt is prev

        #pragma unroll
        for (int kp = 0; kp < 5; ++kp) {
            cur ^= 1;
            char* bb = &b_lds[0][0] + cur * 8192;
            // write this phase's tile (staged one phase ago; vmem landed)
            #pragma unroll
            for (int i = 0; i < 2; ++i)
                *reinterpret_cast<s16x8*>(bb + l_off[i]) = pre[i];
            // issue next tile's loads (consumed next phase)
            {
                int tn  = (nxt < 60) ? nxt : 59; ++nxt;
                int ntn = tn / 5, kpn = tn - ntn * 5;
                const char* gb = WbB + (size_t)ntn * (64 * KD * 2) + kpn * 128;
                #pragma unroll
                for (int i = 0; i < 2; ++i)
                    pre[i] = *reinterpret_cast<const s16x8*>(gb + g_off[i]);
            }
            asm volatile("s_waitcnt lgkmcnt(0)" ::: "memory");
            __builtin_amdgcn_sched_barrier(0);
            __builtin_amdgcn_s_barrier();
            #pragma unroll
            for (int kk = 0; kk < 2; ++kk) {
                const int kt = kp * 2 + kk;
                const char* bs = bb + kk * 4096;
                #pragma unroll
                for (int ni = 0; ni < 4; ++ni) {
                    bf16x8 bf = *reinterpret_cast<const bf16x8*>(bs + ni * 1024 + roff);
                    acc[0][ni] = __builtin_amdgcn_mfma_f32_16x16x32_bf16(afr[0][kt], bf, acc[0][ni], 0, 0, 0);
                    acc[1][ni] = __builtin_amdgcn_mfma_f32_16x16x32_bf16(afr[1][kt], bf, acc[1][ni], 0, 0, 0);
                }
            }
            // dribble prev-nt stores (fire-and-forget, keeps DRAM pipe fed)
            if (pn0 >= 0) {
                #pragma unroll
                for (int si = S0[kp]; si < S1[kp]; ++si) {
                    const int j  = si & 3;
                    const int rb = (si >> 2) & 1;
                    const int ni = si >> 3;
                    out[(size_t)(obase[rb][j] + pn0 + ni * 16 + lrow)] =
                        accP[rb][ni][j] + bvP[ni];
                }
            }
        }
    };

    f32x4 accA[2][4], accB[2][4];
    float bvA[4], bvB[4];
    #pragma unroll
    for (int p = 0; p < 6; ++p) {
        do_nt(accA, bvA, accB, bvB, (2 * p) * 64,     2 * p * 64 - 64);
        do_nt(accB, bvB, accA, bvA, (2 * p + 1) * 64, (2 * p + 1) * 64 - 64);
    }
    // tail: store last nt (accB, n0 = 11*64)
    #pragma unroll
    for (int si = 0; si < 32; ++si) {
        const int j  = si & 3;
        const int rb = (si >> 2) & 1;
        const int ni = si >> 3;
        out[(size_t)(obase[rb][j] + 704 + ni * 16 + lrow)] = accB[rb][ni][j] + bvB[ni];
    }
}

extern "C" void kernel_launch(void* const* d_in, const int* in_sizes, int n_in,
                              void* d_out, int out_size, void* d_ws, size_t ws_size,
                              hipStream_t stream) {
    const float* x    = (const float*)d_in[0];
    const float* ea   = (const float*)d_in[1];
    const float* P    = (const float*)d_in[2];
    const float* EV   = (const float*)d_in[3];
    const float* EEv  = (const float*)d_in[4];
    const float* W    = (const float*)d_in[5];
    const float* bias = (const float*)d_in[6];
    const float* gt   = (const float*)d_in[7];
    const int* eidx   = (const int*)d_in[8];
    const int* batch  = (const int*)d_in[9];

    float* out = (float*)d_out;
    u16* Wb  = (u16*)d_ws;
    int* ints = (int*)((char*)d_ws + (size_t)KD * HD * 2);
    int *nptr = ints, *eptr = ints + 32;

    ptr_k<<<1, 64, 0, stream>>>(batch, eidx, nptr, eptr);
    wconv_k<<<(KD * HD + 255) / 256, 256, 0, stream>>>(W, Wb);
    aux_k<<<(int)(((size_t)NG * HD + MASK_ELEMS + 255) / 256), 256, 0, stream>>>(gt, out);
    gemm_scatter<<<dim3((NN + NE) / 128), 256, 0, stream>>>(
        x, ea, P, EV, EEv, bias, eidx, batch, Wb, nptr, eptr, out);
}